// Round 10
// baseline (149.005 us; speedup 1.0000x reference)
//
#include <hip/hip_runtime.h>
#include <float.h>
#include <math.h>

#define Bc 512
#define Sc 100
#define Hc 1024
#define Ac 128
#define Nc 8
#define AS_ST 68
#define BS_ST 132

// ---------------- K0: positional-encoding table pe[S][H] ----------------
__global__ __launch_bounds__(256) void pe_kernel(float* __restrict__ pe){
  int s = blockIdx.x;
  int t = threadIdx.x;
  const float fac = (float)(-9.210340371976184 / 1024.0);  // -ln(10000)/H
  for(int i = t; i < Hc/2; i += 256){
    float div = expf((float)(2*i) * fac);
    float a = (float)s * div;
    pe[s*Hc + 2*i]     = sinf(a);
    pe[s*Hc + 2*i + 1] = cosf(a);
  }
}

// ---------------- K1: xs[b][h] = sum_s (x[b,s,h] + pe[s,h])  (single kernel per b) ----------------
// 1024 thr: 4 s-groups x 256 h-chunks; LDS combine. pe rows are L2-resident (400KB),
// absorbed in parallel with the x HBM stream. Replaces pesum+xsum+xsred (3 kernels).
__global__ __launch_bounds__(1024) void xsum_fused(const float* __restrict__ x, const float* __restrict__ pe,
                                                   float* __restrict__ xs){
  __shared__ float4 part[3][256];      // partials for s-groups 1..3 (12 KB)
  int b = blockIdx.x;
  int t = threadIdx.x;
  int sg = t >> 8, hc = t & 255;
  const float4* xr = (const float4*)(x + (size_t)b*Sc*Hc);
  const float4* pr = (const float4*)pe;
  float4 acc = make_float4(0.f,0.f,0.f,0.f);
  int s0 = sg*25;
  #pragma unroll 5
  for(int s = s0; s < s0+25; ++s){
    float4 v = xr[s*256 + hc];
    float4 p = pr[s*256 + hc];
    acc.x += v.x + p.x;
    acc.y += v.y + p.y;
    acc.z += v.z + p.z;
    acc.w += v.w + p.w;
  }
  if(sg) part[sg-1][hc] = acc;
  __syncthreads();
  if(sg == 0){
    #pragma unroll
    for(int i = 0; i < 3; ++i){
      float4 p = part[i][hc];
      acc.x += p.x; acc.y += p.y; acc.z += p.z; acc.w += p.w;
    }
    ((float4*)(xs + (size_t)b*Hc))[hc] = acc;
  }
}

// ---------------- K2: Ksum4[ks][b][j] = sum_{k in slice ks(256)} xs[b][k] * Wk[j][k] ----------------
// 64x128 tile, 4x8 frag, k-split 4, software-pipelined staging.
__global__ __launch_bounds__(256) void ksum_gemm2(const float* __restrict__ xs, const float* __restrict__ Wk,
                                                  float* __restrict__ Ksum4){
  __shared__ float As[32*AS_ST];   // [kk][m]  8.7 KB
  __shared__ float Bs[32*BS_ST];   // [kk][j] 16.9 KB
  const int t = threadIdx.x;
  const int j0 = blockIdx.x*128, b0 = blockIdx.y*64, ks = blockIdx.z;
  const int ty = t>>4, tx = t&15;
  float acc[4][8];
  #pragma unroll
  for(int i = 0; i < 4; ++i)
    #pragma unroll
    for(int j = 0; j < 8; ++j) acc[i][j] = 0.f;

  const int kb = ks*256;
  float4 af[2], bf[4], afn[2], bfn[4];
  #pragma unroll
  for(int i = 0; i < 2; ++i){
    int id = t + i*256; int m = id>>3, q = id&7;
    af[i] = *(const float4*)(xs + ((size_t)(b0+m)<<10) + kb + q*4);
  }
  #pragma unroll
  for(int i = 0; i < 4; ++i){
    int id = t + i*256; int r = id>>3, c = id&7;
    bf[i] = *(const float4*)(Wk + ((size_t)(j0+r)<<10) + kb + c*4);
  }

  for(int c0 = 0; c0 < 8; ++c0){
    __syncthreads();                 // previous chunk's LDS reads complete
    #pragma unroll
    for(int i = 0; i < 2; ++i){
      int id = t + i*256; int m = id>>3, q = id&7;
      As[(q*4+0)*AS_ST + m] = af[i].x;
      As[(q*4+1)*AS_ST + m] = af[i].y;
      As[(q*4+2)*AS_ST + m] = af[i].z;
      As[(q*4+3)*AS_ST + m] = af[i].w;
    }
    #pragma unroll
    for(int i = 0; i < 4; ++i){
      int id = t + i*256; int r = id>>3, c = id&7;
      Bs[(c*4+0)*BS_ST + r] = bf[i].x;
      Bs[(c*4+1)*BS_ST + r] = bf[i].y;
      Bs[(c*4+2)*BS_ST + r] = bf[i].z;
      Bs[(c*4+3)*BS_ST + r] = bf[i].w;
    }
    if(c0 < 7){                      // prefetch next chunk during compute
      int k0 = kb + (c0+1)*32;
      #pragma unroll
      for(int i = 0; i < 2; ++i){
        int id = t + i*256; int m = id>>3, q = id&7;
        afn[i] = *(const float4*)(xs + ((size_t)(b0+m)<<10) + k0 + q*4);
      }
      #pragma unroll
      for(int i = 0; i < 4; ++i){
        int id = t + i*256; int r = id>>3, c = id&7;
        bfn[i] = *(const float4*)(Wk + ((size_t)(j0+r)<<10) + k0 + c*4);
      }
    }
    __syncthreads();                 // chunk staged
    #pragma unroll 8
    for(int kk = 0; kk < 32; ++kk){
      float4 a4 = *(const float4*)&As[kk*AS_ST + ty*4];
      float4 bu = *(const float4*)&Bs[kk*BS_ST + tx*4];
      float4 bv = *(const float4*)&Bs[kk*BS_ST + 64 + tx*4];
      float a[4] = {a4.x, a4.y, a4.z, a4.w};
      float bb[8] = {bu.x,bu.y,bu.z,bu.w, bv.x,bv.y,bv.z,bv.w};
      #pragma unroll
      for(int i = 0; i < 4; ++i)
        #pragma unroll
        for(int j = 0; j < 8; ++j)
          acc[i][j] = fmaf(a[i], bb[j], acc[i][j]);
    }
    af[0]=afn[0]; af[1]=afn[1];
    bf[0]=bfn[0]; bf[1]=bfn[1]; bf[2]=bfn[2]; bf[3]=bfn[3];
  }
  #pragma unroll
  for(int i = 0; i < 4; ++i){
    float* cp = Ksum4 + (((size_t)ks*Bc + b0 + ty*4 + i)<<10) + j0 + tx*4;
    *(float4*)cp        = make_float4(acc[i][0],acc[i][1],acc[i][2],acc[i][3]);
    *(float4*)(cp + 64) = make_float4(acc[i][4],acc[i][5],acc[i][6],acc[i][7]);
  }
}

// ---------------- K3: v[b][n][h] = sum_a (sum_ks Ksum4[ks][b][n*A+a]) * Wq[n*A+a][h] ----------------
// ksred FUSED into A-staging (4 slices summed on load; Ksum4=8MB is L2-resident).
__global__ __launch_bounds__(256) void v_gemm2(const float* __restrict__ Ksum4, const float* __restrict__ Wq,
                                               float* __restrict__ v){
  __shared__ float As[32*AS_ST];
  __shared__ float Bs[32*BS_ST];
  const int t = threadIdx.x;
  const int h0 = blockIdx.x*128, b0 = blockIdx.y*64, n = blockIdx.z;
  const int ty = t>>4, tx = t&15;
  const size_t sl = (size_t)Bc*Hc;
  float acc[4][8];
  #pragma unroll
  for(int i = 0; i < 4; ++i)
    #pragma unroll
    for(int j = 0; j < 8; ++j) acc[i][j] = 0.f;

  float4 af[2], bf[4], afn[2], bfn[4];
  #pragma unroll
  for(int i = 0; i < 2; ++i){
    int id = t + i*256; int m = id>>3, q = id&7;
    const float* ap = Ksum4 + ((size_t)(b0+m)<<10) + n*Ac + q*4;
    float4 a0 = *(const float4*)(ap);
    float4 a1 = *(const float4*)(ap + sl);
    float4 a2 = *(const float4*)(ap + 2*sl);
    float4 a3 = *(const float4*)(ap + 3*sl);
    af[i] = make_float4(a0.x+a1.x+a2.x+a3.x, a0.y+a1.y+a2.y+a3.y,
                        a0.z+a1.z+a2.z+a3.z, a0.w+a1.w+a2.w+a3.w);
  }
  #pragma unroll
  for(int i = 0; i < 4; ++i){
    int id = t + i*256; int kk = id>>5, q = id&31;
    bf[i] = *(const float4*)(Wq + ((size_t)(n*Ac + kk)<<10) + h0 + q*4);
  }

  for(int c0 = 0; c0 < 4; ++c0){
    __syncthreads();
    #pragma unroll
    for(int i = 0; i < 2; ++i){
      int id = t + i*256; int m = id>>3, q = id&7;
      As[(q*4+0)*AS_ST + m] = af[i].x;
      As[(q*4+1)*AS_ST + m] = af[i].y;
      As[(q*4+2)*AS_ST + m] = af[i].z;
      As[(q*4+3)*AS_ST + m] = af[i].w;
    }
    #pragma unroll
    for(int i = 0; i < 4; ++i){
      int id = t + i*256; int kk = id>>5, q = id&31;
      *(float4*)&Bs[kk*BS_ST + q*4] = bf[i];
    }
    if(c0 < 3){
      int k0 = (c0+1)*32;
      #pragma unroll
      for(int i = 0; i < 2; ++i){
        int id = t + i*256; int m = id>>3, q = id&7;
        const float* ap = Ksum4 + ((size_t)(b0+m)<<10) + n*Ac + k0 + q*4;
        float4 a0 = *(const float4*)(ap);
        float4 a1 = *(const float4*)(ap + sl);
        float4 a2 = *(const float4*)(ap + 2*sl);
        float4 a3 = *(const float4*)(ap + 3*sl);
        afn[i] = make_float4(a0.x+a1.x+a2.x+a3.x, a0.y+a1.y+a2.y+a3.y,
                             a0.z+a1.z+a2.z+a3.z, a0.w+a1.w+a2.w+a3.w);
      }
      #pragma unroll
      for(int i = 0; i < 4; ++i){
        int id = t + i*256; int kk = id>>5, q = id&31;
        bfn[i] = *(const float4*)(Wq + ((size_t)(n*Ac + k0 + kk)<<10) + h0 + q*4);
      }
    }
    __syncthreads();
    #pragma unroll 8
    for(int kk = 0; kk < 32; ++kk){
      float4 a4 = *(const float4*)&As[kk*AS_ST + ty*4];
      float4 bu = *(const float4*)&Bs[kk*BS_ST + tx*4];
      float4 bv = *(const float4*)&Bs[kk*BS_ST + 64 + tx*4];
      float a[4] = {a4.x, a4.y, a4.z, a4.w};
      float bb[8] = {bu.x,bu.y,bu.z,bu.w, bv.x,bv.y,bv.z,bv.w};
      #pragma unroll
      for(int i = 0; i < 4; ++i)
        #pragma unroll
        for(int j = 0; j < 8; ++j)
          acc[i][j] = fmaf(a[i], bb[j], acc[i][j]);
    }
    af[0]=afn[0]; af[1]=afn[1];
    bf[0]=bfn[0]; bf[1]=bfn[1]; bf[2]=bfn[2]; bf[3]=bfn[3];
  }
  #pragma unroll
  for(int i = 0; i < 4; ++i){
    float* cp = v + (((size_t)(b0 + ty*4 + i)*Nc + n)<<10) + h0 + tx*4;
    *(float4*)cp        = make_float4(acc[i][0],acc[i][1],acc[i][2],acc[i][3]);
    *(float4*)(cp + 64) = make_float4(acc[i][4],acc[i][5],acc[i][6],acc[i][7]);
  }
}

// ---------------- K4: x.v logits -> +gumbel -> argmax_s -> gather rows of x ----------------
// Round-4 attn (best proven).
__global__ __launch_bounds__(1024) void attn_kernel(const float* __restrict__ x, const float* __restrict__ pe,
                                                    const float* __restrict__ v, const float* __restrict__ g,
                                                    float* __restrict__ out){
  __shared__ float4 tile[1600];        // [r<100][16 slots], 16B-slot XOR swizzle, 25.6 KB
  __shared__ float part[8][Nc][104];   // [kq][n][s] 26.6 KB
  __shared__ int sidx[Nc];
  const int b = blockIdx.x;
  const int t = threadIdx.x;
  const int lane = t & 63;
  const int w  = __builtin_amdgcn_readfirstlane(t >> 6);  // wave id 0..15
  const int kq = w & 7, sh = w >> 3;

  const int r1 = t >> 4, c1 = t & 15;
  const bool has2 = (t < 576);
  const int e2 = t + 1024;
  const int r2 = e2 >> 4, c2 = e2 & 15;

  const float* xb = x + (size_t)b*Sc*Hc;
  const float* vb = v + (size_t)b*Nc*Hc;

  int rw = sh*64 + lane;               // 0..127
  int r  = (rw < Sc) ? rw : (Sc-1);
  const bool valid = (rw < Sc);

  float acc[Nc];
  #pragma unroll
  for(int n = 0; n < Nc; ++n) acc[n] = 0.f;

  float4 xv1 = *(const float4*)(xb + r1*Hc + c1*4);
  float4 pv1 = *(const float4*)(pe + r1*Hc + c1*4);
  float4 xv2 = make_float4(0,0,0,0), pv2 = make_float4(0,0,0,0);
  if(has2){ xv2 = *(const float4*)(xb + r2*Hc + c2*4);
            pv2 = *(const float4*)(pe + r2*Hc + c2*4); }

  for(int kt = 0; kt < 16; ++kt){
    __syncthreads();
    tile[r1*16 + (c1 ^ (r1&7))] = make_float4(xv1.x+pv1.x, xv1.y+pv1.y, xv1.z+pv1.z, xv1.w+pv1.w);
    if(has2)
      tile[r2*16 + (c2 ^ (r2&7))] = make_float4(xv2.x+pv2.x, xv2.y+pv2.y, xv2.z+pv2.z, xv2.w+pv2.w);
    if(kt < 15){
      int ko = (kt+1)*64;
      xv1 = *(const float4*)(xb + r1*Hc + ko + c1*4);
      pv1 = *(const float4*)(pe + r1*Hc + ko + c1*4);
      if(has2){ xv2 = *(const float4*)(xb + r2*Hc + ko + c2*4);
                pv2 = *(const float4*)(pe + r2*Hc + ko + c2*4); }
    }
    __syncthreads();
    #pragma unroll
    for(int j = 0; j < 2; ++j){
      float4 xe = tile[r*16 + ((kq*2 + j) ^ (r&7))];
      const float* vk = vb + kt*64 + kq*8 + j*4;
      #pragma unroll
      for(int n = 0; n < Nc; ++n){
        const float* vn = vk + n*Hc;
        acc[n] = fmaf(xe.x, vn[0], acc[n]);
        acc[n] = fmaf(xe.y, vn[1], acc[n]);
        acc[n] = fmaf(xe.z, vn[2], acc[n]);
        acc[n] = fmaf(xe.w, vn[3], acc[n]);
      }
    }
  }
  if(valid){
    #pragma unroll
    for(int n = 0; n < Nc; ++n) part[kq][n][rw] = acc[n];
  }
  __syncthreads();

  if(w < Nc){
    int n = w, j = lane;
    float best = -FLT_MAX; int bidx = 0;
    #pragma unroll
    for(int i = 0; i < 2; ++i){
      int s2 = j + 64*i;
      if(s2 < Sc){
        float dot = 0.f;
        #pragma unroll
        for(int q = 0; q < 8; ++q) dot += part[q][n][s2];
        float y = dot/3200.0f + g[(size_t)(b*Nc + n)*Sc + s2];
        if(y > best){ best = y; bidx = s2; }   // strict > keeps first index (jnp tie rule)
      }
    }
    #pragma unroll
    for(int m = 32; m >= 1; m >>= 1){
      float ob = __shfl_xor(best, m, 64);
      int   oi = __shfl_xor(bidx, m, 64);
      if(ob > best || (ob == best && oi < bidx)){ best = ob; bidx = oi; }
    }
    if(j == 0) sidx[n] = bidx;
  }
  __syncthreads();

  const float4* xb4 = (const float4*)xb;
  float4* ob4 = (float4*)(out + (size_t)b*Nc*Hc);
  #pragma unroll
  for(int i = 0; i < 2; ++i){
    int idx = i*1024 + t;
    int nn = idx >> 8, c = idx & 255;
    ob4[idx] = xb4[sidx[nn]*256 + c];
  }
}

extern "C" void kernel_launch(void* const* d_in, const int* in_sizes, int n_in,
                              void* d_out, int out_size, void* d_ws, size_t ws_size,
                              hipStream_t stream) {
  const float* x  = (const float*)d_in[0];   // [512,100,1024]
  const float* Wq = (const float*)d_in[1];   // [1024,1024]
  const float* Wk = (const float*)d_in[2];   // [1024,1024]
  const float* g  = (const float*)d_in[3];   // [4096,100]
  float* out = (float*)d_out;                // [512,8,1024]

  char* ws = (char*)d_ws;
  float* pe    = (float*)(ws);                //    409,600 B
  float* xs    = (float*)(ws +    409600);    //  2,097,152 B  [512][1024]
  float* Ksum4 = (float*)(ws +   2506752);    //  8,388,608 B  [4][512][1024]
  float* v     = (float*)(ws +  10895360);    // 16,777,216 B  (total ~27.7 MB)

  pe_kernel  <<<100, 256, 0, stream>>>(pe);
  xsum_fused <<<512, 1024, 0, stream>>>(x, pe, xs);
  ksum_gemm2 <<<dim3(8,8,4), 256, 0, stream>>>(xs, Wk, Ksum4);
  v_gemm2    <<<dim3(8,8,8), 256, 0, stream>>>(Ksum4, Wq, v);
  attn_kernel<<<512, 1024, 0, stream>>>(x, pe, v, g, out);
}